// Round 7
// baseline (1447.633 us; speedup 1.0000x reference)
//
#include <hip/hip_runtime.h>
#include <hip/hip_bf16.h>

#define BB 16384
#define NN 54
#define TT 80
#define HH 48
#define PH 80
#define SHH 32
#define AA 397
#define EPSF 1e-5f

typedef __hip_bfloat16 bf16;

__device__ __forceinline__ float tof(float x){ return x; }
__device__ __forceinline__ float tof(bf16 x){ return __bfloat162float(x); }
__device__ __forceinline__ void stor(float* p, float v){ *p = v; }
__device__ __forceinline__ void stor(bf16* p, float v){ *p = __float2bfloat16(v); }

// mish(x) = x * tanh(softplus(x)) = x * w/(w+2), w = e*(2+e), e = exp(x)
__device__ __forceinline__ float mishf(float x){
    float e = __expf(fminf(x, 15.f));
    float w = e * (2.f + e);
    return x * w / (w + 2.f);
}

// unpack 2 bf16 packed in a u32 -> 2 floats
__device__ __forceinline__ void unpack2(unsigned u, float* x){
    x[0] = __uint_as_float(u << 16);
    x[1] = __uint_as_float(u & 0xffff0000u);
}

__device__ __forceinline__ float bperm(int byteaddr, float v){
    return __int_as_float(__builtin_amdgcn_ds_bpermute(byteaddr, __float_as_int(v)));
}

// 48-elem dot, W wave-uniform (scalar loads), x in VGPRs; 4 chains for ILP
__device__ __forceinline__ float dot48(const float* __restrict__ w,
                                       const float* __restrict__ x){
    float d0 = 0.f, d1 = 0.f, d2 = 0.f, d3 = 0.f;
    #pragma unroll
    for (int h = 0; h < HH; h += 4){
        d0 += w[h+0]*x[h+0];
        d1 += w[h+1]*x[h+1];
        d2 += w[h+2]*x[h+2];
        d3 += w[h+3]*x[h+3];
    }
    return (d0 + d1) + (d2 + d3);
}

struct P30 { const void* a[30]; };

// ---- packed-weight workspace layout (fp32 element offsets) ----
#define OFF_WtT   0                     // [80][128] tn-part weights: sett|city|road|0
#define OFF_WnT   (OFF_WtT + 80*128)    // [48][128] (kept for compat, unused by k_heads)
#define OFF_B1P   (OFF_WnT + 48*128)    // [128] layer-1 biases (dst cols = 0)
#define OFF_WRT   (OFF_B1P + 128)       // [80][32] robber tn-part
#define OFF_WRN   (OFF_WRT + 80*32)     // [48][32] robber tile-part (unused by k_heads)
#define OFF_RB1   (OFF_WRN + 48*32)     // [32] rob1_b
#define OFF_W2P   (OFF_RB1 + 32)        // [96] sett2_w|city2_w|road2_w
#define OFF_ROB2  (OFF_W2P + 96)        // [5][32] rob2_w
#define OFF_B2S   (OFF_ROB2 + 160)      // [8] sett2_b,city2_b,road2_b,rob2_b[5]
#define OFF_LNW   (OFF_B2S + 8)         // [48] ln_n_w
#define OFF_LNB   (OFF_LNW + 48)        // [48] ln_n_b
#define OFF_B2G   (OFF_LNB + 48)        // [122] gfc2_b at surviving cols
#define OFF_WG1T  (OFF_B2G + 122)       // [80][80] gfc1_w transposed
#define OFF_B1G   (OFF_WG1T + 80*80)    // [80] gfc1_b
#define OFF_WG2T  (OFF_B1G + 80)        // [80][122] gfc2_w transposed, surviving cols
#define OFF_WKH   (OFF_WG2T + 80*122)   // [5][32][48] node-part weights, k-major:
                                        //   sett|city|roadS|roadD|robber
#define PK_TOTAL  (OFF_WKH + 5*32*48)

// Runtime dtype probe + zero the batchnorm accumulators
__global__ void k_detect(const unsigned short* tr, int* flag,
                         float* bn_sum, float* bn_sq){
    int t = threadIdx.x;
    if (t < PH){ bn_sum[t] = 0.f; bn_sq[t] = 0.f; }
    if (t == 0){
        int good = 0;
        for (int i = 0; i < 1024; i += 2){
            int e = (tr[i] >> 7) & 0xFF;
            if (e >= 117 && e <= 137) good++;
        }
        *flag = (good > 256) ? 1 : 0;   // 1 = bf16, 0 = float32
    }
}

// ---------------- K0: pack/transpose all head weights to fp32 ----------------
template<typename T>
__device__ void prep_body(P30 p, float* pk){
    const T* sett1_w=(const T*)p.a[14]; const T* sett1_b=(const T*)p.a[15];
    const T* sett2_w=(const T*)p.a[16]; const T* sett2_b=(const T*)p.a[17];
    const T* city1_w=(const T*)p.a[18]; const T* city1_b=(const T*)p.a[19];
    const T* city2_w=(const T*)p.a[20]; const T* city2_b=(const T*)p.a[21];
    const T* road1_w=(const T*)p.a[22]; const T* road1_b=(const T*)p.a[23];
    const T* road2_w=(const T*)p.a[24]; const T* road2_b=(const T*)p.a[25];
    const T* rob1_w =(const T*)p.a[26]; const T* rob1_b =(const T*)p.a[27];
    const T* rob2_w =(const T*)p.a[28]; const T* rob2_b =(const T*)p.a[29];
    const T* gfc1_w =(const T*)p.a[8];  const T* gfc1_b =(const T*)p.a[9];
    const T* gfc2_w =(const T*)p.a[12]; const T* gfc2_b =(const T*)p.a[13];
    const T* ln_n_w =(const T*)p.a[6];  const T* ln_n_b =(const T*)p.a[7];

    int gid = blockIdx.x*blockDim.x + threadIdx.x;
    int gsz = gridDim.x*blockDim.x;

    for (int i=gid; i<80*128; i+=gsz){ int k=i>>7, j=i&127; float v;
        if (j<32)      v = tof(sett1_w[j*128+k]);
        else if (j<64) v = tof(city1_w[(j-32)*128+k]);
        else if (j<96) v = tof(road1_w[(j-64)*176+k]);
        else           v = 0.f;
        pk[OFF_WtT+i]=v; }
    for (int i=gid; i<128; i+=gsz){ float v;
        if (i<32) v=tof(sett1_b[i]); else if (i<64) v=tof(city1_b[i-32]);
        else if (i<96) v=tof(road1_b[i-64]); else v=0.f;
        pk[OFF_B1P+i]=v; }
    for (int i=gid; i<80*32; i+=gsz){ int k=i>>5, h=i&31; pk[OFF_WRT+i]=tof(rob1_w[h*128+k]); }
    for (int i=gid; i<32; i+=gsz) pk[OFF_RB1+i]=tof(rob1_b[i]);
    for (int i=gid; i<96; i+=gsz){ float v;
        if (i<32) v=tof(sett2_w[i]); else if (i<64) v=tof(city2_w[i-32]); else v=tof(road2_w[i-64]);
        pk[OFF_W2P+i]=v; }
    for (int i=gid; i<160; i+=gsz) pk[OFF_ROB2+i]=tof(rob2_w[i]);
    for (int i=gid; i<8; i+=gsz){ float v;
        if (i==0) v=tof(sett2_b[0]); else if (i==1) v=tof(city2_b[0]);
        else if (i==2) v=tof(road2_b[0]); else v=tof(rob2_b[i-3]);
        pk[OFF_B2S+i]=v; }
    for (int i=gid; i<48; i+=gsz){ pk[OFF_LNW+i]=tof(ln_n_w[i]); pk[OFF_LNB+i]=tof(ln_n_b[i]); }
    for (int i=gid; i<122; i+=gsz){ int col = (i<5)? i : (280+i-5); pk[OFF_B2G+i]=tof(gfc2_b[col]); }
    for (int i=gid; i<80*80; i+=gsz){ int k=i/80, j=i%80; pk[OFF_WG1T+i]=tof(gfc1_w[j*80+k]); }
    for (int i=gid; i<80; i+=gsz) pk[OFF_B1G+i]=tof(gfc1_b[i]);
    for (int i=gid; i<80*122; i+=gsz){ int k=i/122, g=i-k*122;
        int col = (g<5)? g : (280+g-5);
        pk[OFF_WG2T+i]=tof(gfc2_w[col*PH+k]); }
    // k-major node-part weights for streaming-k heads: [head][k][h]
    for (int i=gid; i<5*32*48; i+=gsz){
        int head = i / (32*48);
        int rem  = i - head*32*48;
        int k = rem / 48, h = rem - k*48;
        float v;
        if      (head == 0) v = tof(sett1_w[k*128 +  80 + h]);
        else if (head == 1) v = tof(city1_w[k*128 +  80 + h]);
        else if (head == 2) v = tof(road1_w[k*176 +  80 + h]);
        else if (head == 3) v = tof(road1_w[k*176 + 128 + h]);
        else                v = tof(rob1_w [k*128 +  80 + h]);
        pk[OFF_WKH+i] = v;
    }
}

__global__ void k_prep(P30 p, float* pk, const int* __restrict__ flag){
    if (*flag) prep_body<bf16>(p, pk); else prep_body<float>(p, pk);
}

// ---------------- K1: 8-row batch: trunk LN + [gfc1 | tp | rtp] GEMM ----------------
template<typename T>
__device__ void tn8_body(const T* __restrict__ trunk,
                         const T* __restrict__ lw, const T* __restrict__ lb,
                         const float* __restrict__ pk,
                         float* __restrict__ hbuf, float* __restrict__ tpr,
                         float* __restrict__ bn_sum, float* __restrict__ bn_sq,
                         float* __restrict__ s_tnT){   // [80][12]
    int tid = threadIdx.x, wave = tid >> 6, lane = tid & 63;
    int row0 = blockIdx.x * 8;
    for (int r2 = 0; r2 < 2; ++r2){
        int rb = wave*2 + r2;
        const T* tr = trunk + (size_t)(row0 + rb) * TT;
        float x0 = (lane < TT)      ? tof(tr[lane])      : 0.f;
        float x1 = (lane + 64 < TT) ? tof(tr[lane + 64]) : 0.f;
        float s = x0 + x1;
        for (int m = 32; m; m >>= 1) s += __shfl_xor(s, m, 64);
        float mu = s / TT;
        float d0 = (lane < TT)      ? (x0 - mu) : 0.f;
        float d1 = (lane + 64 < TT) ? (x1 - mu) : 0.f;
        float v = d0*d0 + d1*d1;
        for (int m = 32; m; m >>= 1) v += __shfl_xor(v, m, 64);
        float rstd = rsqrtf(v / TT + EPSF);
        if (lane < TT)
            s_tnT[lane*12 + rb] = d0 * rstd * tof(lw[lane]) + tof(lb[lane]);
        if (lane + 64 < TT)
            s_tnT[(lane+64)*12 + rb] = d1 * rstd * tof(lw[lane+64]) + tof(lb[lane+64]);
    }
    __syncthreads();
    if (tid < 240){
        const float* wp; int stride; float bias; float* ob; int ostride;
        if (tid < 80){
            wp = pk + OFF_WG1T + tid; stride = 80;  bias = pk[OFF_B1G + tid];
            ob = hbuf + (size_t)row0*80 + tid;  ostride = 80;
        } else if (tid < 208){
            int j = tid - 80;
            wp = pk + OFF_WtT + j;  stride = 128; bias = pk[OFF_B1P + j];
            ob = tpr + (size_t)row0*160 + j;    ostride = 160;
        } else {
            int j = tid - 208;
            wp = pk + OFF_WRT + j;  stride = 32;  bias = pk[OFF_RB1 + j];
            ob = tpr + (size_t)row0*160 + 128 + j; ostride = 160;
        }
        float acc[8];
        #pragma unroll
        for (int r = 0; r < 8; ++r) acc[r] = bias;
        #pragma unroll 4
        for (int k = 0; k < TT; ++k){
            float wv = wp[k*stride];
            float4 a = *(const float4*)&s_tnT[k*12];
            float4 b = *(const float4*)&s_tnT[k*12 + 4];
            acc[0] += wv*a.x; acc[1] += wv*a.y; acc[2] += wv*a.z; acc[3] += wv*a.w;
            acc[4] += wv*b.x; acc[5] += wv*b.y; acc[6] += wv*b.z; acc[7] += wv*b.w;
        }
        #pragma unroll
        for (int r = 0; r < 8; ++r) ob[r*ostride] = acc[r];
        if (tid < 80){
            float s8 = 0.f, q8 = 0.f;
            #pragma unroll
            for (int r = 0; r < 8; ++r){ s8 += acc[r]; q8 += acc[r]*acc[r]; }
            atomicAdd(bn_sum + tid, s8);
            atomicAdd(bn_sq  + tid, q8);
        }
    }
}

__global__ __launch_bounds__(256) void k_tn8(P30 p, const float* pk, float* hbuf,
                                             float* tpr, float* bn_sum, float* bn_sq,
                                             const int* __restrict__ flag){
    __shared__ float s_tnT[80*12];
    if (*flag)
        tn8_body<bf16>((const bf16*)p.a[0], (const bf16*)p.a[4], (const bf16*)p.a[5],
                       pk, hbuf, tpr, bn_sum, bn_sq, s_tnT);
    else
        tn8_body<float>((const float*)p.a[0], (const float*)p.a[4], (const float*)p.a[5],
                        pk, hbuf, tpr, bn_sum, bn_sq, s_tnT);
}

// ---------------- K2: batchnorm scale/shift from accumulated sums ----------------
__global__ void k_bnstats2(P30 p, const float* __restrict__ bn_sum,
                           const float* __restrict__ bn_sq,
                           float* scale, float* shift, const int* __restrict__ flag){
    int f = threadIdx.x;
    if (f < PH){
        float mu  = bn_sum[f] * (1.f/BB);
        float var = bn_sq[f]  * (1.f/BB) - mu*mu;
        float bw, bb;
        if (*flag){ bw = tof(((const bf16*)p.a[10])[f]); bb = tof(((const bf16*)p.a[11])[f]); }
        else      { bw = ((const float*)p.a[10])[f];     bb = ((const float*)p.a[11])[f]; }
        float sc = rsqrtf(var + EPSF) * bw;
        scale[f] = sc;
        shift[f] = bb - mu * sc;
    }
}

// ---------------- K3: global head, 16 rows per block ----------------
template<typename T>
__device__ void ghead_body(const float* __restrict__ hbuf,
                           const float* __restrict__ scale, const float* __restrict__ shift,
                           const float* __restrict__ pk, T* __restrict__ out,
                           float* __restrict__ s_mT){   // [80][20]
    int tid = threadIdx.x;
    int row0 = blockIdx.x * 16;
    const float* wg2t = pk + OFF_WG2T;
    const float* b2g  = pk + OFF_B2G;
    for (int i = tid; i < 1280; i += 256){
        int r = i / 80, k = i - r*80;
        float hv = hbuf[(size_t)(row0 + r)*80 + k];
        s_mT[k*20 + r] = mishf(hv * scale[k] + shift[k]);
    }
    __syncthreads();
    int g = tid & 127, half = tid >> 7, r0 = half * 8;
    if (g < 122){
        float acc[8] = {0,0,0,0,0,0,0,0};
        #pragma unroll 4
        for (int k = 0; k < 80; ++k){
            float wv = wg2t[k*122 + g];
            float4 a = *(const float4*)&s_mT[k*20 + r0];
            float4 b = *(const float4*)&s_mT[k*20 + r0 + 4];
            acc[0] += wv*a.x; acc[1] += wv*a.y; acc[2] += wv*a.z; acc[3] += wv*a.w;
            acc[4] += wv*b.x; acc[5] += wv*b.y; acc[6] += wv*b.z; acc[7] += wv*b.w;
        }
        int col = (g < 5) ? g : (280 + g - 5);
        float bg = b2g[g];
        #pragma unroll
        for (int r = 0; r < 8; ++r)
            stor(out + (size_t)(row0 + r0 + r)*AA + col, acc[r] + bg);
    }
}

__global__ __launch_bounds__(256) void k_ghead(const float* hbuf, const float* scale,
                                               const float* shift, const float* pk,
                                               void* out, const int* __restrict__ flag){
    __shared__ float s_mT[80*20];
    if (*flag) ghead_body<bf16>(hbuf, scale, shift, pk, (bf16*)out, s_mT);
    else       ghead_body<float>(hbuf, scale, shift, pk, (float*)out, s_mT);
}

// ---------------- K4: wave-per-row, streaming-k, barrier-free heads ----------------
template<typename T>
__device__ void heads_body(const T* __restrict__ node_emb,
                           const int* __restrict__ road_pairs,
                           const int* __restrict__ tile_nodes,
                           const float* __restrict__ tpr,
                           const float* __restrict__ pk,
                           T* __restrict__ out){
    const float* Ws    = pk + OFF_WKH;             // [32][48]
    const float* Wc    = Ws  + 32*48;
    const float* Wrs   = Wc  + 32*48;
    const float* Wrd   = Wrs + 32*48;
    const float* Wrb   = Wrd + 32*48;
    const float* w2p   = pk + OFF_W2P;
    const float* rob2p = pk + OFF_ROB2;
    const float* b2s   = pk + OFF_B2S;
    const float* lnw   = pk + OFF_LNW;
    const float* lnb   = pk + OFF_LNB;

    int tid  = threadIdx.x;
    int wave = __builtin_amdgcn_readfirstlane(tid >> 6);
    int lane = tid & 63;
    int row  = blockIdx.x*4 + wave;
    const float* tpr_row = tpr + (size_t)row*160;   // wave-uniform -> scalar loads
    T* orow = out + (size_t)row*AA;

    // ---- node LN into registers (lane = node) ----
    float x[HH];
    {
        int n = (lane < NN) ? lane : (NN-1);
        const T* ne = node_emb + ((size_t)row*NN + n)*HH;
        if constexpr (sizeof(T) == 2){
            const uint4* v = (const uint4*)ne;     // 48 bf16 = 6 x 16B
            #pragma unroll
            for (int i = 0; i < 6; ++i){
                uint4 u = v[i];
                unpack2(u.x, x + i*8 + 0); unpack2(u.y, x + i*8 + 2);
                unpack2(u.z, x + i*8 + 4); unpack2(u.w, x + i*8 + 6);
            }
        } else {
            const float4* v = (const float4*)ne;   // 48 f32 = 12 x 16B
            #pragma unroll
            for (int i = 0; i < 12; ++i){
                float4 f = v[i];
                x[i*4] = f.x; x[i*4+1] = f.y; x[i*4+2] = f.z; x[i*4+3] = f.w;
            }
        }
        float s = 0.f, q = 0.f;
        #pragma unroll
        for (int i = 0; i < HH; ++i){ s += x[i]; q += x[i]*x[i]; }
        float mu   = s * (1.f/HH);
        float var  = q * (1.f/HH) - mu*mu;
        float rstd = rsqrtf(fmaxf(var, 0.f) + EPSF);
        #pragma unroll
        for (int i = 0; i < HH; ++i) x[i] = (x[i] - mu)*rstd*lnw[i] + lnb[i];
    }

    // ---- settlement head: streaming-k, scalar output accumulator ----
    {
        float o = b2s[0];
        #pragma unroll 4
        for (int k = 0; k < 32; ++k)
            o += mishf(tpr_row[k] + dot48(Ws + k*48, x)) * w2p[k];
        if (lane < NN) stor(orow + 5 + lane, o);
    }
    // ---- city head ----
    {
        float o = b2s[1];
        #pragma unroll 4
        for (int k = 0; k < 32; ++k)
            o += mishf(tpr_row[32+k] + dot48(Wc + k*48, x)) * w2p[32+k];
        if (lane < NN) stor(orow + 59 + lane, o);
    }
    // ---- robber head: per-node proj streamed, tile-mean via bpermute ----
    {
        int t = (lane < 19) ? lane : 18;
        const int* t6 = tile_nodes + t*6;
        int a0 = t6[0]*4, a1 = t6[1]*4, a2 = t6[2]*4,
            a3 = t6[3]*4, a4 = t6[4]*4, a5 = t6[5]*4;
        float acc5[5];
        #pragma unroll
        for (int i = 0; i < 5; ++i) acc5[i] = b2s[3+i];
        const float* rtp = tpr_row + 128;
        #pragma unroll 4
        for (int k = 0; k < 32; ++k){
            float rk = dot48(Wrb + k*48, x);
            float s = bperm(a0, rk) + bperm(a1, rk) + bperm(a2, rk)
                    + bperm(a3, rk) + bperm(a4, rk) + bperm(a5, rk);
            float m = mishf(rtp[k] + s * (1.f/6.f));
            acc5[0] += m * rob2p[k];      acc5[1] += m * rob2p[32+k];
            acc5[2] += m * rob2p[64+k];   acc5[3] += m * rob2p[96+k];
            acc5[4] += m * rob2p[128+k];
        }
        if (lane < 19){
            #pragma unroll
            for (int i = 0; i < 5; ++i) stor(orow + 185 + lane*5 + i, acc5[i]);
        }
    }
    // ---- road head: src/dst proj streamed, mix via bpermute ----
    {
        int r1 = lane;                 // roads 0..63
        int r2 = 64 + (lane & 7);      // roads 64..71 (lanes 0..7 store)
        int s1 = road_pairs[2*r1]*4,   d1 = road_pairs[2*r1+1]*4;
        int s2 = road_pairs[2*r2]*4,   d2 = road_pairs[2*r2+1]*4;
        float o1 = b2s[2], o2 = b2s[2];
        const float* tpk = tpr_row + 64;
        #pragma unroll 4
        for (int k = 0; k < 32; ++k){
            float sk = dot48(Wrs + k*48, x);
            float dk = dot48(Wrd + k*48, x);
            float tk = tpk[k], wk = w2p[64+k];
            o1 += mishf(tk + bperm(s1, sk) + bperm(d1, dk)) * wk;
            o2 += mishf(tk + bperm(s2, sk) + bperm(d2, dk)) * wk;
        }
        stor(orow + 113 + r1, o1);
        if (lane < 8) stor(orow + 113 + r2, o2);
    }
}

__global__ __launch_bounds__(256, 4) void k_heads(P30 p, const float* tpr, const float* pk,
                                                  void* out, const int* __restrict__ flag){
    if (*flag)
        heads_body<bf16>((const bf16*)p.a[1], (const int*)p.a[2], (const int*)p.a[3],
                         tpr, pk, (bf16*)out);
    else
        heads_body<float>((const float*)p.a[1], (const int*)p.a[2], (const int*)p.a[3],
                          tpr, pk, (float*)out);
}

extern "C" void kernel_launch(void* const* d_in, const int* in_sizes, int n_in,
                              void* d_out, int out_size, void* d_ws, size_t ws_size,
                              hipStream_t stream){
    P30 p;
    for (int i = 0; i < 30; ++i) p.a[i] = d_in[i];

    int*   flag   = (int*)d_ws;
    float* bn_sum = (float*)((char*)d_ws + 256);        // 80
    float* bn_sq  = bn_sum + PH;                        // 80
    float* scale  = bn_sq + PH;                         // 80
    float* shift  = scale + PH;                         // 80
    float* hbuf   = (float*)((char*)d_ws + 2048);       // BB*80
    float* tpr    = hbuf + (size_t)BB*PH;               // BB*160
    float* pk     = tpr + (size_t)BB*160;               // PK_TOTAL packed weights

    k_detect<<<1, 128, 0, stream>>>((const unsigned short*)d_in[0], flag, bn_sum, bn_sq);
    k_prep<<<64, 256, 0, stream>>>(p, pk, flag);
    k_tn8<<<BB/8, 256, 0, stream>>>(p, pk, hbuf, tpr, bn_sum, bn_sq, flag);
    k_bnstats2<<<1, 128, 0, stream>>>(p, bn_sum, bn_sq, scale, shift, flag);
    k_ghead<<<BB/16, 256, 0, stream>>>(hbuf, scale, shift, pk, d_out, flag);
    k_heads<<<BB/4, 256, 0, stream>>>(p, tpr, pk, d_out, flag);
}

// Round 8
// 1292.526 us; speedup vs baseline: 1.1200x; 1.1200x over previous
//
#include <hip/hip_runtime.h>
#include <hip/hip_bf16.h>

#define BB 16384
#define NN 54
#define TT 80
#define HH 48
#define PH 80
#define SHH 32
#define AA 397
#define EPSF 1e-5f

typedef __hip_bfloat16 bf16;

__device__ __forceinline__ float tof(float x){ return x; }
__device__ __forceinline__ float tof(bf16 x){ return __bfloat162float(x); }
__device__ __forceinline__ void stor(float* p, float v){ *p = v; }
__device__ __forceinline__ void stor(bf16* p, float v){ *p = __float2bfloat16(v); }

// mish(x) = x * tanh(softplus(x)) = x * w/(w+2), w = e*(2+e), e = exp(x)
__device__ __forceinline__ float mishf(float x){
    float e = __expf(fminf(x, 15.f));
    float w = e * (2.f + e);
    return x * w / (w + 2.f);
}

// unpack 2 bf16 packed in a u32 -> 2 floats
__device__ __forceinline__ void unpack2(unsigned u, float* x){
    x[0] = __uint_as_float(u << 16);
    x[1] = __uint_as_float(u & 0xffff0000u);
}

__device__ __forceinline__ float bperm(int byteaddr, float v){
    return __int_as_float(__builtin_amdgcn_ds_bpermute(byteaddr, __float_as_int(v)));
}

// 48-elem dot, W wave-uniform (scalar loads), x in VGPRs; 4 chains for ILP
__device__ __forceinline__ float dot48(const float* __restrict__ w,
                                       const float* __restrict__ x){
    float d0 = 0.f, d1 = 0.f, d2 = 0.f, d3 = 0.f;
    #pragma unroll
    for (int h = 0; h < HH; h += 4){
        d0 += w[h+0]*x[h+0];
        d1 += w[h+1]*x[h+1];
        d2 += w[h+2]*x[h+2];
        d3 += w[h+3]*x[h+3];
    }
    return (d0 + d1) + (d2 + d3);
}

struct P30 { const void* a[30]; };

// ---- packed-weight workspace layout (fp32 element offsets) ----
#define OFF_WtT   0                     // [80][128] tn-part weights: sett|city|road|0
#define OFF_WnT   (OFF_WtT + 80*128)    // [48][128] (kept for compat, unused by k_heads)
#define OFF_B1P   (OFF_WnT + 48*128)    // [128] layer-1 biases (dst cols = 0)
#define OFF_WRT   (OFF_B1P + 128)       // [80][32] robber tn-part
#define OFF_WRN   (OFF_WRT + 80*32)     // [48][32] robber tile-part (unused by k_heads)
#define OFF_RB1   (OFF_WRN + 48*32)     // [32] rob1_b
#define OFF_W2P   (OFF_RB1 + 32)        // [96] sett2_w|city2_w|road2_w
#define OFF_ROB2  (OFF_W2P + 96)        // [5][32] rob2_w
#define OFF_B2S   (OFF_ROB2 + 160)      // [8] sett2_b,city2_b,road2_b,rob2_b[5]
#define OFF_LNW   (OFF_B2S + 8)         // [48] ln_n_w
#define OFF_LNB   (OFF_LNW + 48)        // [48] ln_n_b
#define OFF_B2G   (OFF_LNB + 48)        // [122] gfc2_b at surviving cols
#define OFF_WG1T  (OFF_B2G + 122)       // [80][80] gfc1_w transposed
#define OFF_B1G   (OFF_WG1T + 80*80)    // [80] gfc1_b
#define OFF_WG2T  (OFF_B1G + 80)        // [80][122] gfc2_w transposed, surviving cols
#define OFF_WKH   (OFF_WG2T + 80*122)   // [5][32][48] node-part weights, k-major:
                                        //   sett|city|roadS|roadD|robber
#define PK_TOTAL  (OFF_WKH + 5*32*48)

// Runtime dtype probe + zero the batchnorm accumulators
__global__ void k_detect(const unsigned short* tr, int* flag,
                         float* bn_sum, float* bn_sq){
    int t = threadIdx.x;
    if (t < PH){ bn_sum[t] = 0.f; bn_sq[t] = 0.f; }
    if (t == 0){
        int good = 0;
        for (int i = 0; i < 1024; i += 2){
            int e = (tr[i] >> 7) & 0xFF;
            if (e >= 117 && e <= 137) good++;
        }
        *flag = (good > 256) ? 1 : 0;   // 1 = bf16, 0 = float32
    }
}

// ---------------- K0: pack/transpose all head weights to fp32 ----------------
template<typename T>
__device__ void prep_body(P30 p, float* pk){
    const T* sett1_w=(const T*)p.a[14]; const T* sett1_b=(const T*)p.a[15];
    const T* sett2_w=(const T*)p.a[16]; const T* sett2_b=(const T*)p.a[17];
    const T* city1_w=(const T*)p.a[18]; const T* city1_b=(const T*)p.a[19];
    const T* city2_w=(const T*)p.a[20]; const T* city2_b=(const T*)p.a[21];
    const T* road1_w=(const T*)p.a[22]; const T* road1_b=(const T*)p.a[23];
    const T* road2_w=(const T*)p.a[24]; const T* road2_b=(const T*)p.a[25];
    const T* rob1_w =(const T*)p.a[26]; const T* rob1_b =(const T*)p.a[27];
    const T* rob2_w =(const T*)p.a[28]; const T* rob2_b =(const T*)p.a[29];
    const T* gfc1_w =(const T*)p.a[8];  const T* gfc1_b =(const T*)p.a[9];
    const T* gfc2_w =(const T*)p.a[12]; const T* gfc2_b =(const T*)p.a[13];
    const T* ln_n_w =(const T*)p.a[6];  const T* ln_n_b =(const T*)p.a[7];

    int gid = blockIdx.x*blockDim.x + threadIdx.x;
    int gsz = gridDim.x*blockDim.x;

    for (int i=gid; i<80*128; i+=gsz){ int k=i>>7, j=i&127; float v;
        if (j<32)      v = tof(sett1_w[j*128+k]);
        else if (j<64) v = tof(city1_w[(j-32)*128+k]);
        else if (j<96) v = tof(road1_w[(j-64)*176+k]);
        else           v = 0.f;
        pk[OFF_WtT+i]=v; }
    for (int i=gid; i<128; i+=gsz){ float v;
        if (i<32) v=tof(sett1_b[i]); else if (i<64) v=tof(city1_b[i-32]);
        else if (i<96) v=tof(road1_b[i-64]); else v=0.f;
        pk[OFF_B1P+i]=v; }
    for (int i=gid; i<80*32; i+=gsz){ int k=i>>5, h=i&31; pk[OFF_WRT+i]=tof(rob1_w[h*128+k]); }
    for (int i=gid; i<32; i+=gsz) pk[OFF_RB1+i]=tof(rob1_b[i]);
    for (int i=gid; i<96; i+=gsz){ float v;
        if (i<32) v=tof(sett2_w[i]); else if (i<64) v=tof(city2_w[i-32]); else v=tof(road2_w[i-64]);
        pk[OFF_W2P+i]=v; }
    for (int i=gid; i<160; i+=gsz) pk[OFF_ROB2+i]=tof(rob2_w[i]);
    for (int i=gid; i<8; i+=gsz){ float v;
        if (i==0) v=tof(sett2_b[0]); else if (i==1) v=tof(city2_b[0]);
        else if (i==2) v=tof(road2_b[0]); else v=tof(rob2_b[i-3]);
        pk[OFF_B2S+i]=v; }
    for (int i=gid; i<48; i+=gsz){ pk[OFF_LNW+i]=tof(ln_n_w[i]); pk[OFF_LNB+i]=tof(ln_n_b[i]); }
    for (int i=gid; i<122; i+=gsz){ int col = (i<5)? i : (280+i-5); pk[OFF_B2G+i]=tof(gfc2_b[col]); }
    for (int i=gid; i<80*80; i+=gsz){ int k=i/80, j=i%80; pk[OFF_WG1T+i]=tof(gfc1_w[j*80+k]); }
    for (int i=gid; i<80; i+=gsz) pk[OFF_B1G+i]=tof(gfc1_b[i]);
    for (int i=gid; i<80*122; i+=gsz){ int k=i/122, g=i-k*122;
        int col = (g<5)? g : (280+g-5);
        pk[OFF_WG2T+i]=tof(gfc2_w[col*PH+k]); }
    // k-major node-part weights for streaming-k heads: [head][k][h]
    for (int i=gid; i<5*32*48; i+=gsz){
        int head = i / (32*48);
        int rem  = i - head*32*48;
        int k = rem / 48, h = rem - k*48;
        float v;
        if      (head == 0) v = tof(sett1_w[k*128 +  80 + h]);
        else if (head == 1) v = tof(city1_w[k*128 +  80 + h]);
        else if (head == 2) v = tof(road1_w[k*176 +  80 + h]);
        else if (head == 3) v = tof(road1_w[k*176 + 128 + h]);
        else                v = tof(rob1_w [k*128 +  80 + h]);
        pk[OFF_WKH+i] = v;
    }
}

__global__ void k_prep(P30 p, float* pk, const int* __restrict__ flag){
    if (*flag) prep_body<bf16>(p, pk); else prep_body<float>(p, pk);
}

// ---------------- K1: 8-row batch: trunk LN + [gfc1 | tp | rtp] GEMM ----------------
template<typename T>
__device__ void tn8_body(const T* __restrict__ trunk,
                         const T* __restrict__ lw, const T* __restrict__ lb,
                         const float* __restrict__ pk,
                         float* __restrict__ hbuf, float* __restrict__ tpr,
                         float* __restrict__ bn_sum, float* __restrict__ bn_sq,
                         float* __restrict__ s_tnT){   // [80][12]
    int tid = threadIdx.x, wave = tid >> 6, lane = tid & 63;
    int row0 = blockIdx.x * 8;
    for (int r2 = 0; r2 < 2; ++r2){
        int rb = wave*2 + r2;
        const T* tr = trunk + (size_t)(row0 + rb) * TT;
        float x0 = (lane < TT)      ? tof(tr[lane])      : 0.f;
        float x1 = (lane + 64 < TT) ? tof(tr[lane + 64]) : 0.f;
        float s = x0 + x1;
        for (int m = 32; m; m >>= 1) s += __shfl_xor(s, m, 64);
        float mu = s / TT;
        float d0 = (lane < TT)      ? (x0 - mu) : 0.f;
        float d1 = (lane + 64 < TT) ? (x1 - mu) : 0.f;
        float v = d0*d0 + d1*d1;
        for (int m = 32; m; m >>= 1) v += __shfl_xor(v, m, 64);
        float rstd = rsqrtf(v / TT + EPSF);
        if (lane < TT)
            s_tnT[lane*12 + rb] = d0 * rstd * tof(lw[lane]) + tof(lb[lane]);
        if (lane + 64 < TT)
            s_tnT[(lane+64)*12 + rb] = d1 * rstd * tof(lw[lane+64]) + tof(lb[lane+64]);
    }
    __syncthreads();
    if (tid < 240){
        const float* wp; int stride; float bias; float* ob; int ostride;
        if (tid < 80){
            wp = pk + OFF_WG1T + tid; stride = 80;  bias = pk[OFF_B1G + tid];
            ob = hbuf + (size_t)row0*80 + tid;  ostride = 80;
        } else if (tid < 208){
            int j = tid - 80;
            wp = pk + OFF_WtT + j;  stride = 128; bias = pk[OFF_B1P + j];
            ob = tpr + (size_t)row0*160 + j;    ostride = 160;
        } else {
            int j = tid - 208;
            wp = pk + OFF_WRT + j;  stride = 32;  bias = pk[OFF_RB1 + j];
            ob = tpr + (size_t)row0*160 + 128 + j; ostride = 160;
        }
        float acc[8];
        #pragma unroll
        for (int r = 0; r < 8; ++r) acc[r] = bias;
        #pragma unroll 4
        for (int k = 0; k < TT; ++k){
            float wv = wp[k*stride];
            float4 a = *(const float4*)&s_tnT[k*12];
            float4 b = *(const float4*)&s_tnT[k*12 + 4];
            acc[0] += wv*a.x; acc[1] += wv*a.y; acc[2] += wv*a.z; acc[3] += wv*a.w;
            acc[4] += wv*b.x; acc[5] += wv*b.y; acc[6] += wv*b.z; acc[7] += wv*b.w;
        }
        #pragma unroll
        for (int r = 0; r < 8; ++r) ob[r*ostride] = acc[r];
        if (tid < 80){
            float s8 = 0.f, q8 = 0.f;
            #pragma unroll
            for (int r = 0; r < 8; ++r){ s8 += acc[r]; q8 += acc[r]*acc[r]; }
            atomicAdd(bn_sum + tid, s8);
            atomicAdd(bn_sq  + tid, q8);
        }
    }
}

__global__ __launch_bounds__(256) void k_tn8(P30 p, const float* pk, float* hbuf,
                                             float* tpr, float* bn_sum, float* bn_sq,
                                             const int* __restrict__ flag){
    __shared__ float s_tnT[80*12];
    if (*flag)
        tn8_body<bf16>((const bf16*)p.a[0], (const bf16*)p.a[4], (const bf16*)p.a[5],
                       pk, hbuf, tpr, bn_sum, bn_sq, s_tnT);
    else
        tn8_body<float>((const float*)p.a[0], (const float*)p.a[4], (const float*)p.a[5],
                        pk, hbuf, tpr, bn_sum, bn_sq, s_tnT);
}

// ---------------- K2: batchnorm scale/shift from accumulated sums ----------------
__global__ void k_bnstats2(P30 p, const float* __restrict__ bn_sum,
                           const float* __restrict__ bn_sq,
                           float* scale, float* shift, const int* __restrict__ flag){
    int f = threadIdx.x;
    if (f < PH){
        float mu  = bn_sum[f] * (1.f/BB);
        float var = bn_sq[f]  * (1.f/BB) - mu*mu;
        float bw, bb;
        if (*flag){ bw = tof(((const bf16*)p.a[10])[f]); bb = tof(((const bf16*)p.a[11])[f]); }
        else      { bw = ((const float*)p.a[10])[f];     bb = ((const float*)p.a[11])[f]; }
        float sc = rsqrtf(var + EPSF) * bw;
        scale[f] = sc;
        shift[f] = bb - mu * sc;
    }
}

// ---------------- K3: global head, 16 rows per block ----------------
template<typename T>
__device__ void ghead_body(const float* __restrict__ hbuf,
                           const float* __restrict__ scale, const float* __restrict__ shift,
                           const float* __restrict__ pk, T* __restrict__ out,
                           float* __restrict__ s_mT){   // [80][20]
    int tid = threadIdx.x;
    int row0 = blockIdx.x * 16;
    const float* wg2t = pk + OFF_WG2T;
    const float* b2g  = pk + OFF_B2G;
    for (int i = tid; i < 1280; i += 256){
        int r = i / 80, k = i - r*80;
        float hv = hbuf[(size_t)(row0 + r)*80 + k];
        s_mT[k*20 + r] = mishf(hv * scale[k] + shift[k]);
    }
    __syncthreads();
    int g = tid & 127, half = tid >> 7, r0 = half * 8;
    if (g < 122){
        float acc[8] = {0,0,0,0,0,0,0,0};
        #pragma unroll 4
        for (int k = 0; k < 80; ++k){
            float wv = wg2t[k*122 + g];
            float4 a = *(const float4*)&s_mT[k*20 + r0];
            float4 b = *(const float4*)&s_mT[k*20 + r0 + 4];
            acc[0] += wv*a.x; acc[1] += wv*a.y; acc[2] += wv*a.z; acc[3] += wv*a.w;
            acc[4] += wv*b.x; acc[5] += wv*b.y; acc[6] += wv*b.z; acc[7] += wv*b.w;
        }
        int col = (g < 5) ? g : (280 + g - 5);
        float bg = b2g[g];
        #pragma unroll
        for (int r = 0; r < 8; ++r)
            stor(out + (size_t)(row0 + r0 + r)*AA + col, acc[r] + bg);
    }
}

__global__ __launch_bounds__(256) void k_ghead(const float* hbuf, const float* scale,
                                               const float* shift, const float* pk,
                                               void* out, const int* __restrict__ flag){
    __shared__ float s_mT[80*20];
    if (*flag) ghead_body<bf16>(hbuf, scale, shift, pk, (bf16*)out, s_mT);
    else       ghead_body<float>(hbuf, scale, shift, pk, (float*)out, s_mT);
}

// ---------------- K4: one wave per row (block=64), streaming-k, barrier-free ----------------
template<typename T>
__device__ void heads_body(const T* __restrict__ node_emb,
                           const int* __restrict__ road_pairs,
                           const int* __restrict__ tile_nodes,
                           const float* __restrict__ tpr,
                           const float* __restrict__ pk,
                           T* __restrict__ out){
    const float* Ws    = pk + OFF_WKH;             // [32][48]
    const float* Wc    = Ws  + 32*48;
    const float* Wrs   = Wc  + 32*48;
    const float* Wrd   = Wrs + 32*48;
    const float* Wrb   = Wrd + 32*48;
    const float* w2p   = pk + OFF_W2P;
    const float* rob2p = pk + OFF_ROB2;
    const float* b2s   = pk + OFF_B2S;
    const float* lnw   = pk + OFF_LNW;
    const float* lnb   = pk + OFF_LNB;

    int lane = threadIdx.x & 63;
    int row  = blockIdx.x;
    const float* tpr_row = tpr + (size_t)row*160;   // uniform -> scalar loads
    T* orow = out + (size_t)row*AA;

    // ---- node LN into registers (lane = node) ----
    float x[HH];
    {
        int n = (lane < NN) ? lane : (NN-1);
        const T* ne = node_emb + ((size_t)row*NN + n)*HH;
        if constexpr (sizeof(T) == 2){
            const uint4* v = (const uint4*)ne;     // 48 bf16 = 6 x 16B
            #pragma unroll
            for (int i = 0; i < 6; ++i){
                uint4 u = v[i];
                unpack2(u.x, x + i*8 + 0); unpack2(u.y, x + i*8 + 2);
                unpack2(u.z, x + i*8 + 4); unpack2(u.w, x + i*8 + 6);
            }
        } else {
            const float4* v = (const float4*)ne;   // 48 f32 = 12 x 16B
            #pragma unroll
            for (int i = 0; i < 12; ++i){
                float4 f = v[i];
                x[i*4] = f.x; x[i*4+1] = f.y; x[i*4+2] = f.z; x[i*4+3] = f.w;
            }
        }
        float s = 0.f, q = 0.f;
        #pragma unroll
        for (int i = 0; i < HH; ++i){ s += x[i]; q += x[i]*x[i]; }
        float mu   = s * (1.f/HH);
        float var  = q * (1.f/HH) - mu*mu;
        float rstd = rsqrtf(fmaxf(var, 0.f) + EPSF);
        #pragma unroll
        for (int i = 0; i < HH; ++i) x[i] = (x[i] - mu)*rstd*lnw[i] + lnb[i];
    }

    // ---- settlement head: streaming-k, scalar output accumulator ----
    {
        float o = b2s[0];
        #pragma unroll 4
        for (int k = 0; k < 32; ++k)
            o += mishf(tpr_row[k] + dot48(Ws + k*48, x)) * w2p[k];
        if (lane < NN) stor(orow + 5 + lane, o);
    }
    // ---- city head ----
    {
        float o = b2s[1];
        #pragma unroll 4
        for (int k = 0; k < 32; ++k)
            o += mishf(tpr_row[32+k] + dot48(Wc + k*48, x)) * w2p[32+k];
        if (lane < NN) stor(orow + 59 + lane, o);
    }
    // ---- robber head: per-node proj streamed, tile-mean via bpermute ----
    {
        int t = (lane < 19) ? lane : 18;
        const int* t6 = tile_nodes + t*6;
        int a0 = t6[0]*4, a1 = t6[1]*4, a2 = t6[2]*4,
            a3 = t6[3]*4, a4 = t6[4]*4, a5 = t6[5]*4;
        float acc5[5];
        #pragma unroll
        for (int i = 0; i < 5; ++i) acc5[i] = b2s[3+i];
        const float* rtp = tpr_row + 128;
        #pragma unroll 4
        for (int k = 0; k < 32; ++k){
            float rk = dot48(Wrb + k*48, x);
            float s = bperm(a0, rk) + bperm(a1, rk) + bperm(a2, rk)
                    + bperm(a3, rk) + bperm(a4, rk) + bperm(a5, rk);
            float m = mishf(rtp[k] + s * (1.f/6.f));
            acc5[0] += m * rob2p[k];      acc5[1] += m * rob2p[32+k];
            acc5[2] += m * rob2p[64+k];   acc5[3] += m * rob2p[96+k];
            acc5[4] += m * rob2p[128+k];
        }
        if (lane < 19){
            #pragma unroll
            for (int i = 0; i < 5; ++i) stor(orow + 185 + lane*5 + i, acc5[i]);
        }
    }
    // ---- road head: src/dst proj streamed, mix via bpermute ----
    {
        int r1 = lane;                 // roads 0..63
        int r2 = 64 + (lane & 7);      // roads 64..71 (lanes 0..7 store)
        int s1 = road_pairs[2*r1]*4,   d1 = road_pairs[2*r1+1]*4;
        int s2 = road_pairs[2*r2]*4,   d2 = road_pairs[2*r2+1]*4;
        float o1 = b2s[2], o2 = b2s[2];
        const float* tpk = tpr_row + 64;
        #pragma unroll 4
        for (int k = 0; k < 32; ++k){
            float sk = dot48(Wrs + k*48, x);
            float dk = dot48(Wrd + k*48, x);
            float tk = tpk[k], wk = w2p[64+k];
            o1 += mishf(tk + bperm(s1, sk) + bperm(d1, dk)) * wk;
            o2 += mishf(tk + bperm(s2, sk) + bperm(d2, dk)) * wk;
        }
        stor(orow + 113 + r1, o1);
        if (lane < 8) stor(orow + 113 + r2, o2);
    }
}

__global__ __launch_bounds__(64) void k_heads(P30 p, const float* tpr, const float* pk,
                                              void* out, const int* __restrict__ flag){
    if (*flag)
        heads_body<bf16>((const bf16*)p.a[1], (const int*)p.a[2], (const int*)p.a[3],
                         tpr, pk, (bf16*)out);
    else
        heads_body<float>((const float*)p.a[1], (const int*)p.a[2], (const int*)p.a[3],
                          tpr, pk, (float*)out);
}

extern "C" void kernel_launch(void* const* d_in, const int* in_sizes, int n_in,
                              void* d_out, int out_size, void* d_ws, size_t ws_size,
                              hipStream_t stream){
    P30 p;
    for (int i = 0; i < 30; ++i) p.a[i] = d_in[i];

    int*   flag   = (int*)d_ws;
    float* bn_sum = (float*)((char*)d_ws + 256);        // 80
    float* bn_sq  = bn_sum + PH;                        // 80
    float* scale  = bn_sq + PH;                         // 80
    float* shift  = scale + PH;                         // 80
    float* hbuf   = (float*)((char*)d_ws + 2048);       // BB*80
    float* tpr    = hbuf + (size_t)BB*PH;               // BB*160
    float* pk     = tpr + (size_t)BB*160;               // PK_TOTAL packed weights

    k_detect<<<1, 128, 0, stream>>>((const unsigned short*)d_in[0], flag, bn_sum, bn_sq);
    k_prep<<<64, 256, 0, stream>>>(p, pk, flag);
    k_tn8<<<BB/8, 256, 0, stream>>>(p, pk, hbuf, tpr, bn_sum, bn_sq, flag);
    k_bnstats2<<<1, 128, 0, stream>>>(p, bn_sum, bn_sq, scale, shift, flag);
    k_ghead<<<BB/16, 256, 0, stream>>>(hbuf, scale, shift, pk, d_out, flag);
    k_heads<<<BB, 64, 0, stream>>>(p, tpr, pk, d_out, flag);
}

// Round 9
// 1013.269 us; speedup vs baseline: 1.4287x; 1.2756x over previous
//
#include <hip/hip_runtime.h>
#include <hip/hip_bf16.h>

#define BB 16384
#define NN 54
#define TT 80
#define HH 48
#define PH 80
#define SHH 32
#define AA 397
#define EPSF 1e-5f

typedef __hip_bfloat16 bf16;

__device__ __forceinline__ float tof(float x){ return x; }
__device__ __forceinline__ float tof(bf16 x){ return __bfloat162float(x); }
__device__ __forceinline__ void stor(float* p, float v){ *p = v; }
__device__ __forceinline__ void stor(bf16* p, float v){ *p = __float2bfloat16(v); }

// mish(x) = x * tanh(softplus(x)) = x * w/(w+2), w = e*(2+e), e = exp(x)
__device__ __forceinline__ float mishf(float x){
    float e = __expf(fminf(x, 15.f));
    float w = e * (2.f + e);
    return x * w / (w + 2.f);
}

// unpack 2 bf16 packed in a u32 -> 2 floats
__device__ __forceinline__ void unpack2(unsigned u, float* x){
    x[0] = __uint_as_float(u << 16);
    x[1] = __uint_as_float(u & 0xffff0000u);
}

__device__ __forceinline__ float bperm(int byteaddr, float v){
    return __int_as_float(__builtin_amdgcn_ds_bpermute(byteaddr, __float_as_int(v)));
}

// two-row 48-dot sharing one weight fetch: w wave-uniform (s_loads), x* in VGPRs
__device__ __forceinline__ void dot48x2(const float* __restrict__ w,
                                        const float* __restrict__ xa,
                                        const float* __restrict__ xb,
                                        float& ra, float& rb){
    float a0=0.f,a1=0.f,a2=0.f,a3=0.f, b0=0.f,b1=0.f,b2=0.f,b3=0.f;
    #pragma unroll
    for (int h = 0; h < HH; h += 4){
        float w0=w[h], w1=w[h+1], w2=w[h+2], w3=w[h+3];
        a0 += w0*xa[h];   b0 += w0*xb[h];
        a1 += w1*xa[h+1]; b1 += w1*xb[h+1];
        a2 += w2*xa[h+2]; b2 += w2*xb[h+2];
        a3 += w3*xa[h+3]; b3 += w3*xb[h+3];
    }
    ra = (a0+a1)+(a2+a3);
    rb = (b0+b1)+(b2+b3);
}

struct P30 { const void* a[30]; };

// ---- packed-weight workspace layout (fp32 element offsets) ----
#define OFF_WtT   0                     // [80][128] tn-part weights: sett|city|road|0
#define OFF_WnT   (OFF_WtT + 80*128)    // [48][128] (kept for compat, unused by k_heads)
#define OFF_B1P   (OFF_WnT + 48*128)    // [128] layer-1 biases (dst cols = 0)
#define OFF_WRT   (OFF_B1P + 128)       // [80][32] robber tn-part
#define OFF_WRN   (OFF_WRT + 80*32)     // [48][32] robber tile-part (unused by k_heads)
#define OFF_RB1   (OFF_WRN + 48*32)     // [32] rob1_b
#define OFF_W2P   (OFF_RB1 + 32)        // [96] sett2_w|city2_w|road2_w
#define OFF_ROB2  (OFF_W2P + 96)        // [5][32] rob2_w
#define OFF_B2S   (OFF_ROB2 + 160)      // [8] sett2_b,city2_b,road2_b,rob2_b[5]
#define OFF_LNW   (OFF_B2S + 8)         // [48] ln_n_w
#define OFF_LNB   (OFF_LNW + 48)        // [48] ln_n_b
#define OFF_B2G   (OFF_LNB + 48)        // [122] gfc2_b at surviving cols
#define OFF_WG1T  (OFF_B2G + 122)       // [80][80] gfc1_w transposed
#define OFF_B1G   (OFF_WG1T + 80*80)    // [80] gfc1_b
#define OFF_WG2T  (OFF_B1G + 80)        // [80][122] gfc2_w transposed, surviving cols
#define OFF_WKH   (OFF_WG2T + 80*122)   // [5][32][48] node-part weights, k-major:
                                        //   sett|city|roadS|roadD|robber
#define PK_TOTAL  (OFF_WKH + 5*32*48)

// Runtime dtype probe + zero the batchnorm accumulators
__global__ void k_detect(const unsigned short* tr, int* flag,
                         float* bn_sum, float* bn_sq){
    int t = threadIdx.x;
    if (t < PH){ bn_sum[t] = 0.f; bn_sq[t] = 0.f; }
    if (t == 0){
        int good = 0;
        for (int i = 0; i < 1024; i += 2){
            int e = (tr[i] >> 7) & 0xFF;
            if (e >= 117 && e <= 137) good++;
        }
        *flag = (good > 256) ? 1 : 0;   // 1 = bf16, 0 = float32
    }
}

// ---------------- K0: pack/transpose all head weights to fp32 ----------------
template<typename T>
__device__ void prep_body(P30 p, float* pk){
    const T* sett1_w=(const T*)p.a[14]; const T* sett1_b=(const T*)p.a[15];
    const T* sett2_w=(const T*)p.a[16]; const T* sett2_b=(const T*)p.a[17];
    const T* city1_w=(const T*)p.a[18]; const T* city1_b=(const T*)p.a[19];
    const T* city2_w=(const T*)p.a[20]; const T* city2_b=(const T*)p.a[21];
    const T* road1_w=(const T*)p.a[22]; const T* road1_b=(const T*)p.a[23];
    const T* road2_w=(const T*)p.a[24]; const T* road2_b=(const T*)p.a[25];
    const T* rob1_w =(const T*)p.a[26]; const T* rob1_b =(const T*)p.a[27];
    const T* rob2_w =(const T*)p.a[28]; const T* rob2_b =(const T*)p.a[29];
    const T* gfc1_w =(const T*)p.a[8];  const T* gfc1_b =(const T*)p.a[9];
    const T* gfc2_w =(const T*)p.a[12]; const T* gfc2_b =(const T*)p.a[13];
    const T* ln_n_w =(const T*)p.a[6];  const T* ln_n_b =(const T*)p.a[7];

    int gid = blockIdx.x*blockDim.x + threadIdx.x;
    int gsz = gridDim.x*blockDim.x;

    for (int i=gid; i<80*128; i+=gsz){ int k=i>>7, j=i&127; float v;
        if (j<32)      v = tof(sett1_w[j*128+k]);
        else if (j<64) v = tof(city1_w[(j-32)*128+k]);
        else if (j<96) v = tof(road1_w[(j-64)*176+k]);
        else           v = 0.f;
        pk[OFF_WtT+i]=v; }
    for (int i=gid; i<128; i+=gsz){ float v;
        if (i<32) v=tof(sett1_b[i]); else if (i<64) v=tof(city1_b[i-32]);
        else if (i<96) v=tof(road1_b[i-64]); else v=0.f;
        pk[OFF_B1P+i]=v; }
    for (int i=gid; i<80*32; i+=gsz){ int k=i>>5, h=i&31; pk[OFF_WRT+i]=tof(rob1_w[h*128+k]); }
    for (int i=gid; i<32; i+=gsz) pk[OFF_RB1+i]=tof(rob1_b[i]);
    for (int i=gid; i<96; i+=gsz){ float v;
        if (i<32) v=tof(sett2_w[i]); else if (i<64) v=tof(city2_w[i-32]); else v=tof(road2_w[i-64]);
        pk[OFF_W2P+i]=v; }
    for (int i=gid; i<160; i+=gsz) pk[OFF_ROB2+i]=tof(rob2_w[i]);
    for (int i=gid; i<8; i+=gsz){ float v;
        if (i==0) v=tof(sett2_b[0]); else if (i==1) v=tof(city2_b[0]);
        else if (i==2) v=tof(road2_b[0]); else v=tof(rob2_b[i-3]);
        pk[OFF_B2S+i]=v; }
    for (int i=gid; i<48; i+=gsz){ pk[OFF_LNW+i]=tof(ln_n_w[i]); pk[OFF_LNB+i]=tof(ln_n_b[i]); }
    for (int i=gid; i<122; i+=gsz){ int col = (i<5)? i : (280+i-5); pk[OFF_B2G+i]=tof(gfc2_b[col]); }
    for (int i=gid; i<80*80; i+=gsz){ int k=i/80, j=i%80; pk[OFF_WG1T+i]=tof(gfc1_w[j*80+k]); }
    for (int i=gid; i<80; i+=gsz) pk[OFF_B1G+i]=tof(gfc1_b[i]);
    for (int i=gid; i<80*122; i+=gsz){ int k=i/122, g=i-k*122;
        int col = (g<5)? g : (280+g-5);
        pk[OFF_WG2T+i]=tof(gfc2_w[col*PH+k]); }
    // k-major node-part weights for streaming-k heads: [head][k][h]
    for (int i=gid; i<5*32*48; i+=gsz){
        int head = i / (32*48);
        int rem  = i - head*32*48;
        int k = rem / 48, h = rem - k*48;
        float v;
        if      (head == 0) v = tof(sett1_w[k*128 +  80 + h]);
        else if (head == 1) v = tof(city1_w[k*128 +  80 + h]);
        else if (head == 2) v = tof(road1_w[k*176 +  80 + h]);
        else if (head == 3) v = tof(road1_w[k*176 + 128 + h]);
        else                v = tof(rob1_w [k*128 +  80 + h]);
        pk[OFF_WKH+i] = v;
    }
}

__global__ void k_prep(P30 p, float* pk, const int* __restrict__ flag){
    if (*flag) prep_body<bf16>(p, pk); else prep_body<float>(p, pk);
}

// ---------------- K1: 8-row batch: trunk LN + [gfc1 | tp | rtp] GEMM ----------------
template<typename T>
__device__ void tn8_body(const T* __restrict__ trunk,
                         const T* __restrict__ lw, const T* __restrict__ lb,
                         const float* __restrict__ pk,
                         float* __restrict__ hbuf, float* __restrict__ tpr,
                         float* __restrict__ bn_sum, float* __restrict__ bn_sq,
                         float* __restrict__ s_tnT){   // [80][12]
    int tid = threadIdx.x, wave = tid >> 6, lane = tid & 63;
    int row0 = blockIdx.x * 8;
    for (int r2 = 0; r2 < 2; ++r2){
        int rb = wave*2 + r2;
        const T* tr = trunk + (size_t)(row0 + rb) * TT;
        float x0 = (lane < TT)      ? tof(tr[lane])      : 0.f;
        float x1 = (lane + 64 < TT) ? tof(tr[lane + 64]) : 0.f;
        float s = x0 + x1;
        for (int m = 32; m; m >>= 1) s += __shfl_xor(s, m, 64);
        float mu = s / TT;
        float d0 = (lane < TT)      ? (x0 - mu) : 0.f;
        float d1 = (lane + 64 < TT) ? (x1 - mu) : 0.f;
        float v = d0*d0 + d1*d1;
        for (int m = 32; m; m >>= 1) v += __shfl_xor(v, m, 64);
        float rstd = rsqrtf(v / TT + EPSF);
        if (lane < TT)
            s_tnT[lane*12 + rb] = d0 * rstd * tof(lw[lane]) + tof(lb[lane]);
        if (lane + 64 < TT)
            s_tnT[(lane+64)*12 + rb] = d1 * rstd * tof(lw[lane+64]) + tof(lb[lane+64]);
    }
    __syncthreads();
    if (tid < 240){
        const float* wp; int stride; float bias; float* ob; int ostride;
        if (tid < 80){
            wp = pk + OFF_WG1T + tid; stride = 80;  bias = pk[OFF_B1G + tid];
            ob = hbuf + (size_t)row0*80 + tid;  ostride = 80;
        } else if (tid < 208){
            int j = tid - 80;
            wp = pk + OFF_WtT + j;  stride = 128; bias = pk[OFF_B1P + j];
            ob = tpr + (size_t)row0*160 + j;    ostride = 160;
        } else {
            int j = tid - 208;
            wp = pk + OFF_WRT + j;  stride = 32;  bias = pk[OFF_RB1 + j];
            ob = tpr + (size_t)row0*160 + 128 + j; ostride = 160;
        }
        float acc[8];
        #pragma unroll
        for (int r = 0; r < 8; ++r) acc[r] = bias;
        #pragma unroll 4
        for (int k = 0; k < TT; ++k){
            float wv = wp[k*stride];
            float4 a = *(const float4*)&s_tnT[k*12];
            float4 b = *(const float4*)&s_tnT[k*12 + 4];
            acc[0] += wv*a.x; acc[1] += wv*a.y; acc[2] += wv*a.z; acc[3] += wv*a.w;
            acc[4] += wv*b.x; acc[5] += wv*b.y; acc[6] += wv*b.z; acc[7] += wv*b.w;
        }
        #pragma unroll
        for (int r = 0; r < 8; ++r) ob[r*ostride] = acc[r];
        if (tid < 80){
            float s8 = 0.f, q8 = 0.f;
            #pragma unroll
            for (int r = 0; r < 8; ++r){ s8 += acc[r]; q8 += acc[r]*acc[r]; }
            atomicAdd(bn_sum + tid, s8);
            atomicAdd(bn_sq  + tid, q8);
        }
    }
}

__global__ __launch_bounds__(256) void k_tn8(P30 p, const float* pk, float* hbuf,
                                             float* tpr, float* bn_sum, float* bn_sq,
                                             const int* __restrict__ flag){
    __shared__ float s_tnT[80*12];
    if (*flag)
        tn8_body<bf16>((const bf16*)p.a[0], (const bf16*)p.a[4], (const bf16*)p.a[5],
                       pk, hbuf, tpr, bn_sum, bn_sq, s_tnT);
    else
        tn8_body<float>((const float*)p.a[0], (const float*)p.a[4], (const float*)p.a[5],
                        pk, hbuf, tpr, bn_sum, bn_sq, s_tnT);
}

// ---------------- K2: batchnorm scale/shift from accumulated sums ----------------
__global__ void k_bnstats2(P30 p, const float* __restrict__ bn_sum,
                           const float* __restrict__ bn_sq,
                           float* scale, float* shift, const int* __restrict__ flag){
    int f = threadIdx.x;
    if (f < PH){
        float mu  = bn_sum[f] * (1.f/BB);
        float var = bn_sq[f]  * (1.f/BB) - mu*mu;
        float bw, bb;
        if (*flag){ bw = tof(((const bf16*)p.a[10])[f]); bb = tof(((const bf16*)p.a[11])[f]); }
        else      { bw = ((const float*)p.a[10])[f];     bb = ((const float*)p.a[11])[f]; }
        float sc = rsqrtf(var + EPSF) * bw;
        scale[f] = sc;
        shift[f] = bb - mu * sc;
    }
}

// ---------------- K3: global head, 16 rows per block ----------------
template<typename T>
__device__ void ghead_body(const float* __restrict__ hbuf,
                           const float* __restrict__ scale, const float* __restrict__ shift,
                           const float* __restrict__ pk, T* __restrict__ out,
                           float* __restrict__ s_mT){   // [80][20]
    int tid = threadIdx.x;
    int row0 = blockIdx.x * 16;
    const float* wg2t = pk + OFF_WG2T;
    const float* b2g  = pk + OFF_B2G;
    for (int i = tid; i < 1280; i += 256){
        int r = i / 80, k = i - r*80;
        float hv = hbuf[(size_t)(row0 + r)*80 + k];
        s_mT[k*20 + r] = mishf(hv * scale[k] + shift[k]);
    }
    __syncthreads();
    int g = tid & 127, half = tid >> 7, r0 = half * 8;
    if (g < 122){
        float acc[8] = {0,0,0,0,0,0,0,0};
        #pragma unroll 4
        for (int k = 0; k < 80; ++k){
            float wv = wg2t[k*122 + g];
            float4 a = *(const float4*)&s_mT[k*20 + r0];
            float4 b = *(const float4*)&s_mT[k*20 + r0 + 4];
            acc[0] += wv*a.x; acc[1] += wv*a.y; acc[2] += wv*a.z; acc[3] += wv*a.w;
            acc[4] += wv*b.x; acc[5] += wv*b.y; acc[6] += wv*b.z; acc[7] += wv*b.w;
        }
        int col = (g < 5) ? g : (280 + g - 5);
        float bg = b2g[g];
        #pragma unroll
        for (int r = 0; r < 8; ++r)
            stor(out + (size_t)(row0 + r0 + r)*AA + col, acc[r] + bg);
    }
}

__global__ __launch_bounds__(256) void k_ghead(const float* hbuf, const float* scale,
                                               const float* shift, const float* pk,
                                               void* out, const int* __restrict__ flag){
    __shared__ float s_mT[80*20];
    if (*flag) ghead_body<bf16>(hbuf, scale, shift, pk, (bf16*)out, s_mT);
    else       ghead_body<float>(hbuf, scale, shift, pk, (float*)out, s_mT);
}

// ---------------- K4: wave handles TWO rows, streaming-k, barrier-free ----------------
template<typename T>
__device__ __forceinline__ void load_ln(const T* __restrict__ ne,
                                        const float* __restrict__ lnw,
                                        const float* __restrict__ lnb,
                                        float* __restrict__ x){
    if constexpr (sizeof(T) == 2){
        const uint4* v = (const uint4*)ne;     // 48 bf16 = 6 x 16B
        #pragma unroll
        for (int i = 0; i < 6; ++i){
            uint4 u = v[i];
            unpack2(u.x, x + i*8 + 0); unpack2(u.y, x + i*8 + 2);
            unpack2(u.z, x + i*8 + 4); unpack2(u.w, x + i*8 + 6);
        }
    } else {
        const float4* v = (const float4*)ne;   // 48 f32 = 12 x 16B
        #pragma unroll
        for (int i = 0; i < 12; ++i){
            float4 f = v[i];
            x[i*4] = f.x; x[i*4+1] = f.y; x[i*4+2] = f.z; x[i*4+3] = f.w;
        }
    }
    float s = 0.f, q = 0.f;
    #pragma unroll
    for (int i = 0; i < HH; ++i){ s += x[i]; q += x[i]*x[i]; }
    float mu   = s * (1.f/HH);
    float var  = q * (1.f/HH) - mu*mu;
    float rstd = rsqrtf(fmaxf(var, 0.f) + EPSF);
    #pragma unroll
    for (int i = 0; i < HH; ++i) x[i] = (x[i] - mu)*rstd*lnw[i] + lnb[i];
}

template<typename T>
__device__ void heads_body(const T* __restrict__ node_emb,
                           const int* __restrict__ road_pairs,
                           const int* __restrict__ tile_nodes,
                           const float* __restrict__ tpr,
                           const float* __restrict__ pk,
                           T* __restrict__ out){
    const float* Ws    = pk + OFF_WKH;             // [32][48]
    const float* Wc    = Ws  + 32*48;
    const float* Wrs   = Wc  + 32*48;
    const float* Wrd   = Wrs + 32*48;
    const float* Wrb   = Wrd + 32*48;
    const float* w2p   = pk + OFF_W2P;
    const float* rob2p = pk + OFF_ROB2;
    const float* b2s   = pk + OFF_B2S;
    const float* lnw   = pk + OFF_LNW;
    const float* lnb   = pk + OFF_LNB;

    int tid  = threadIdx.x;
    int wave = __builtin_amdgcn_readfirstlane(tid >> 6);
    int lane = tid & 63;
    size_t rowA = (size_t)blockIdx.x*8 + wave*2;
    size_t rowB = rowA + 1;
    const float* tprA = tpr + rowA*160;     // wave-uniform -> scalar loads
    const float* tprB = tpr + rowB*160;
    T* orowA = out + rowA*AA;
    T* orowB = out + rowB*AA;

    // ---- node LN into registers for both rows (lane = node) ----
    float xA[HH], xB[HH];
    {
        int n = (lane < NN) ? lane : (NN-1);
        load_ln(node_emb + (rowA*NN + n)*HH, lnw, lnb, xA);
        load_ln(node_emb + (rowB*NN + n)*HH, lnw, lnb, xB);
    }

    // ---- settlement head ----
    {
        float oA = b2s[0], oB = b2s[0];
        #pragma unroll 4
        for (int k = 0; k < 32; ++k){
            float dA, dB; dot48x2(Ws + k*48, xA, xB, dA, dB);
            float w2 = w2p[k];
            oA += mishf(tprA[k] + dA) * w2;
            oB += mishf(tprB[k] + dB) * w2;
        }
        if (lane < NN){ stor(orowA + 5 + lane, oA); stor(orowB + 5 + lane, oB); }
    }
    // ---- city head ----
    {
        float oA = b2s[1], oB = b2s[1];
        #pragma unroll 4
        for (int k = 0; k < 32; ++k){
            float dA, dB; dot48x2(Wc + k*48, xA, xB, dA, dB);
            float w2 = w2p[32+k];
            oA += mishf(tprA[32+k] + dA) * w2;
            oB += mishf(tprB[32+k] + dB) * w2;
        }
        if (lane < NN){ stor(orowA + 59 + lane, oA); stor(orowB + 59 + lane, oB); }
    }
    // ---- robber head: per-node proj streamed, tile-mean via bpermute ----
    {
        int t = (lane < 19) ? lane : 18;
        const int* t6 = tile_nodes + t*6;
        int a0 = t6[0]*4, a1 = t6[1]*4, a2 = t6[2]*4,
            a3 = t6[3]*4, a4 = t6[4]*4, a5 = t6[5]*4;
        float aA[5], aB[5];
        #pragma unroll
        for (int i = 0; i < 5; ++i){ aA[i] = b2s[3+i]; aB[i] = b2s[3+i]; }
        const float* rtA = tprA + 128;
        const float* rtB = tprB + 128;
        #pragma unroll 2
        for (int k = 0; k < 32; ++k){
            float rA, rB; dot48x2(Wrb + k*48, xA, xB, rA, rB);
            float sA = bperm(a0, rA) + bperm(a1, rA) + bperm(a2, rA)
                     + bperm(a3, rA) + bperm(a4, rA) + bperm(a5, rA);
            float sB = bperm(a0, rB) + bperm(a1, rB) + bperm(a2, rB)
                     + bperm(a3, rB) + bperm(a4, rB) + bperm(a5, rB);
            float mA = mishf(rtA[k] + sA * (1.f/6.f));
            float mB = mishf(rtB[k] + sB * (1.f/6.f));
            #pragma unroll
            for (int i = 0; i < 5; ++i){
                float rw = rob2p[i*32 + k];
                aA[i] += mA * rw; aB[i] += mB * rw;
            }
        }
        if (lane < 19){
            #pragma unroll
            for (int i = 0; i < 5; ++i){
                stor(orowA + 185 + lane*5 + i, aA[i]);
                stor(orowB + 185 + lane*5 + i, aB[i]);
            }
        }
    }
    // ---- road head: src/dst proj streamed, mix via bpermute ----
    {
        int r1 = lane;                 // roads 0..63
        int r2 = 64 + (lane & 7);      // roads 64..71 (lanes 0..7 store)
        int s1 = road_pairs[2*r1]*4,   d1 = road_pairs[2*r1+1]*4;
        int s2 = road_pairs[2*r2]*4,   d2 = road_pairs[2*r2+1]*4;
        float o1A = b2s[2], o2A = b2s[2], o1B = b2s[2], o2B = b2s[2];
        const float* tkA = tprA + 64;
        const float* tkB = tprB + 64;
        #pragma unroll 2
        for (int k = 0; k < 32; ++k){
            float sA, sB; dot48x2(Wrs + k*48, xA, xB, sA, sB);
            float dA, dB; dot48x2(Wrd + k*48, xA, xB, dA, dB);
            float tA = tkA[k], tB = tkB[k], wk = w2p[64+k];
            o1A += mishf(tA + bperm(s1, sA) + bperm(d1, dA)) * wk;
            o2A += mishf(tA + bperm(s2, sA) + bperm(d2, dA)) * wk;
            o1B += mishf(tB + bperm(s1, sB) + bperm(d1, dB)) * wk;
            o2B += mishf(tB + bperm(s2, sB) + bperm(d2, dB)) * wk;
        }
        stor(orowA + 113 + r1, o1A);
        stor(orowB + 113 + r1, o1B);
        if (lane < 8){
            stor(orowA + 113 + r2, o2A);
            stor(orowB + 113 + r2, o2B);
        }
    }
}

__global__ __launch_bounds__(256) void k_heads(P30 p, const float* tpr, const float* pk,
                                               void* out, const int* __restrict__ flag){
    if (*flag)
        heads_body<bf16>((const bf16*)p.a[1], (const int*)p.a[2], (const int*)p.a[3],
                         tpr, pk, (bf16*)out);
    else
        heads_body<float>((const float*)p.a[1], (const int*)p.a[2], (const int*)p.a[3],
                          tpr, pk, (float*)out);
}

extern "C" void kernel_launch(void* const* d_in, const int* in_sizes, int n_in,
                              void* d_out, int out_size, void* d_ws, size_t ws_size,
                              hipStream_t stream){
    P30 p;
    for (int i = 0; i < 30; ++i) p.a[i] = d_in[i];

    int*   flag   = (int*)d_ws;
    float* bn_sum = (float*)((char*)d_ws + 256);        // 80
    float* bn_sq  = bn_sum + PH;                        // 80
    float* scale  = bn_sq + PH;                         // 80
    float* shift  = scale + PH;                         // 80
    float* hbuf   = (float*)((char*)d_ws + 2048);       // BB*80
    float* tpr    = hbuf + (size_t)BB*PH;               // BB*160
    float* pk     = tpr + (size_t)BB*160;               // PK_TOTAL packed weights

    k_detect<<<1, 128, 0, stream>>>((const unsigned short*)d_in[0], flag, bn_sum, bn_sq);
    k_prep<<<64, 256, 0, stream>>>(p, pk, flag);
    k_tn8<<<BB/8, 256, 0, stream>>>(p, pk, hbuf, tpr, bn_sum, bn_sq, flag);
    k_bnstats2<<<1, 128, 0, stream>>>(p, bn_sum, bn_sq, scale, shift, flag);
    k_ghead<<<BB/16, 256, 0, stream>>>(hbuf, scale, shift, pk, d_out, flag);
    k_heads<<<BB/8, 256, 0, stream>>>(p, tpr, pk, d_out, flag);
}